// Round 14
// baseline (157.629 us; speedup 1.0000x reference)
//
#include <hip/hip_runtime.h>

#define BB 4
#define NN 256
#define DD 256
#define HH 256
#define NEGV -1.0e9f

typedef _Float16 half8 __attribute__((ext_vector_type(8)));
typedef __fp16   fp16x2 __attribute__((ext_vector_type(2)));
typedef float floatx4 __attribute__((ext_vector_type(4)));

// ---------------- prep (R27, kept): 256 blocks x 1024 thr, wave-split K --------
__global__ __launch_bounds__(1024) void prep(const float* __restrict__ X,
                                             const float* __restrict__ W1,
                                             float* __restrict__ S,
                                             float* __restrict__ T,
                                             _Float16* __restrict__ Wst) {
  const int g = blockIdx.x;    // 0..255 -> rows 4g..4g+3; Wst conversion d = g
  const int t = threadIdx.x;   // 0..1023

  __shared__ float xr[4][256];            // 4 KB
  __shared__ float part[2][4][4][256];    // 32 KB  [S/T][row][kq][h]

  if (t < 256) {   // weight conversion for d = g (R13 map, unchanged)
    const float wcv = W1[(size_t)(2 * DD + g) * HH + t];
    const float wdv = W1[(size_t)(3 * DD + g) * HH + t];
    const int ks = g >> 4;
    const int dd = g & 15;
    const int q  = dd >> 2;
    const int e  = (dd & 3) * 2;
    const int hgrp = t >> 4;
    const int ccw  = t & 15;
    _Float16* p = Wst + ((size_t)((ks * 16 + hgrp) * 4 + q) * 16 + ccw) * 8 + e;
    p[0] = (_Float16)wcv;
    p[1] = (_Float16)wdv;
  }

  const int row0 = g * 4;
  xr[t >> 8][t & 255] = X[(size_t)row0 * DD + t];
  __syncthreads();

  const int w    = t >> 6;     // wave 0..15
  const int lane = t & 63;
  const int r    = w >> 2;     // row 0..3
  const int kq   = w & 3;      // K-quarter 0..3
  const int h0   = lane * 4;
  const float* __restrict__ xrow = xr[r];
  const int dbase = kq * 64;

  float sa0 = 0.f, sa1 = 0.f, sa2 = 0.f, sa3 = 0.f;
  float sb0 = 0.f, sb1 = 0.f, sb2 = 0.f, sb3 = 0.f;
#pragma unroll 4
  for (int dd = 0; dd < 64; ++dd) {
    const int d = dbase + dd;
    const float4 wa = *(const float4*)&W1[(size_t)d * HH + h0];
    const float4 wb = *(const float4*)&W1[(size_t)(DD + d) * HH + h0];
    const float x = xrow[d];
    sa0 = fmaf(x, wa.x, sa0); sa1 = fmaf(x, wa.y, sa1);
    sa2 = fmaf(x, wa.z, sa2); sa3 = fmaf(x, wa.w, sa3);
    sb0 = fmaf(x, wb.x, sb0); sb1 = fmaf(x, wb.y, sb1);
    sb2 = fmaf(x, wb.z, sb2); sb3 = fmaf(x, wb.w, sb3);
  }
  *(float4*)&part[0][r][kq][h0] = make_float4(sa0, sa1, sa2, sa3);
  *(float4*)&part[1][r][kq][h0] = make_float4(sb0, sb1, sb2, sb3);
  __syncthreads();

  const int rr = t >> 8, hh = t & 255;
  S[(size_t)(row0 + rr) * HH + hh] =
      (part[0][rr][0][hh] + part[0][rr][1][hh]) +
      (part[0][rr][2][hh] + part[0][rr][3][hh]);
  T[(size_t)(row0 + rr) * HH + hh] =
      (part[1][rr][0][hh] + part[1][rr][1][hh]) +
      (part[1][rr][2][hh] + part[1][rr][3][hh]);
}

__device__ __forceinline__ half8 make_afrag(const float4 xi, const float4 xj) {
  fp16x2 p0 = __builtin_amdgcn_cvt_pkrtz(__builtin_fabsf(xi.x - xj.x), xi.x * xj.x);
  fp16x2 p1 = __builtin_amdgcn_cvt_pkrtz(__builtin_fabsf(xi.y - xj.y), xi.y * xj.y);
  fp16x2 p2 = __builtin_amdgcn_cvt_pkrtz(__builtin_fabsf(xi.z - xj.z), xi.z * xj.z);
  fp16x2 p3 = __builtin_amdgcn_cvt_pkrtz(__builtin_fabsf(xi.w - xj.w), xi.w * xj.w);
  uint4 u;
  u.x = __builtin_bit_cast(unsigned int, p0);
  u.y = __builtin_bit_cast(unsigned int, p1);
  u.z = __builtin_bit_cast(unsigned int, p2);
  u.w = __builtin_bit_cast(unsigned int, p3);
  return __builtin_bit_cast(half8, u);
}

#define MFMA16(af, bf, acc) acc = __builtin_amdgcn_mfma_f32_16x16x32_f16(af, bf, acc, 0, 0, 0)

// Cross-lane adds on the VALU pipe via DPP (R32) — zero DS-pipe ops.
template <int CTRL>
__device__ __forceinline__ float dpp_add(float v) {
  const int s = __builtin_amdgcn_update_dpp(0, __builtin_bit_cast(int, v),
                                            CTRL, 0xF, 0xF, true);
  return v + __builtin_bit_cast(float, s);
}

// ---------------- score: 32j x 64h wave partition (R33) ------------------------
// DS ledger after R32: reduction=0, A-reads ~25us, staging ~3us. A-fragments
// are (j,k)-indexed -> under the old 64j x 32h partition ALL 8 waves read the
// SAME 64KB Af (8x redundant = 512KB DS/block). R33 partition: wave (jh,hq) =
// (w>>2, w&3) owns j-half x h-quarter -> A redundancy 8x->4x (A-read DS
// halves, ~12us removed); B redundancy 1x->2x (Wst L2 655MB->1.3GB, ~2.2TB/s
// per XCD < 4.3 available; R29 proved traffic volume cheap). MFMA count, acc
// regs, B-ring regs, staging, 16-lane butterfly all unchanged; h-sum grouping
// changes (4 quarters vs 8 slices) -> absmax ~3e-5 but not bit-identical.
// Falsifiers: absmax > 1e-4 = remap bug; WRITE > 10MB = spill; score >= 84 ->
// A-redundancy off critical path -> stop at best-known.
__global__ __launch_bounds__(512, 4) void score_mfma(
    const float* __restrict__ X,  const float* __restrict__ b1,
    const float* __restrict__ W2, const float* __restrict__ b2,
    const float* __restrict__ S,  const float* __restrict__ T,
    const _Float16* __restrict__ Wst, float* __restrict__ Sc) {

  const int beta = blockIdx.x;      // 0..639, qt-major (R25 decode)
  const int b    = blockIdx.y;
  int i, qt;
  if (beta < 64)       { qt = 0; i = beta; }
  else if (beta < 192) { qt = 1; i = beta - 64; }
  else if (beta < 384) { qt = 2; i = beta - 192; }
  else                 { qt = 3; i = beta - 384; }
  const int bi    = b * NN + i;
  const int jbase = qt * 64;
  const int isUp  = qt > (i >> 6);  // block-uniform

  const int t     = threadIdx.x;    // 0..511
  const int lane  = t & 63;
  const int w     = t >> 6;         // wave 0..7
  const int jh    = w >> 2;         // j-half 0..1  (32 j each)
  const int hq    = w & 3;          // h-quarter 0..3 (64 h each)
  const int q     = lane >> 4;
  const int cc    = lane & 15;

  __shared__ __align__(16) float    xi_s[DD];
  __shared__ __align__(16) _Float16 Af[32768];   // 64 KB: [kg][jg*4+qw][ccw*8]
  __shared__ float pre_s[HH];
  __shared__ float pre2_s[HH];
  __shared__ float w2_s[HH];
  __shared__ float sc_s[8][32];     // [wave][j-local within its 32]

  if (t < 256) {
    xi_s[t]  = X[(size_t)bi * DD + t];
    pre_s[t] = S[(size_t)bi * HH + t] + b1[t];
  } else {
    const int u = t - 256;
    pre2_s[u] = T[(size_t)bi * HH + u] + b1[u];
    w2_s[u]   = W2[u];
  }

  const float* __restrict__ Tb = T + (size_t)b * NN * HH;
  const float* __restrict__ Sb = S + (size_t)b * NN * HH;

  const int jloc = t & 63;
  const int jg   = jloc >> 4;
  const int ccw  = jloc & 15;
  const float* __restrict__ xjrow = X + (size_t)(b * NN + jbase + jloc) * DD;

  // wave's B base: h-groups hq*4 .. hq*4+3 (h = hq*64 .. hq*64+63)
  const char* __restrict__ bsrc = (const char*)Wst + hq * 4096 + (size_t)lane * 16;

  // B prefetch ring, 2-deep, 4 frags/step (32 regs, same as R32's 4-deep x 2)
  half8 Bf[2][4];
#pragma unroll
  for (int d = 0; d < 2; ++d)
#pragma unroll
    for (int m = 0; m < 4; ++m)
      Bf[d][m] = *(const half8*)(bsrc + (size_t)d * 16384 + m * 1024);

  __syncthreads();                  // header (xi_s) ready

  {                                 // stage full K: 8 frags/thread (unchanged)
#pragma unroll
    for (int idx = 0; idx < 8; ++idx) {
      const int ksqg = w * 8 + idx;             // 0..63 k-quads
      const int d0   = ksqg * 4;
      const int kg   = ksqg >> 2;               // 0..15
      const int qw   = ksqg & 3;
      const float4 xi4 = *(const float4*)&xi_s[d0];
      const float4 xj4 = *(const float4*)(xjrow + d0);
      *(half8*)&Af[kg * 2048 + (jg * 4 + qw) * 128 + ccw * 8] = make_afrag(xi4, xj4);
    }
  }
  __syncthreads();                  // Af ready; K-loop barrier-free, 16 steps

  floatx4 acc0[4], acc1[4];         // [m]: h-tile m for j-tile jg=2jh (acc0) / 2jh+1 (acc1)
#pragma unroll
  for (int u = 0; u < 4; ++u) { acc0[u] = (floatx4)0.f; acc1[u] = (floatx4)0.f; }

  // A 1-ahead from LDS: only the wave's j-half (2 of 4 j-tiles)
  const _Float16* ap0 = &Af[jh * 1024 + lane * 8];
  half8 An0 = *(const half8*)(ap0);
  half8 An1 = *(const half8*)(ap0 + 512);

#pragma unroll
  for (int kg = 0; kg < 16; ++kg) {
    const int s = kg & 1;                       // static under full unroll
    const half8 Bc0 = Bf[s][0], Bc1 = Bf[s][1];
    const half8 Bc2 = Bf[s][2], Bc3 = Bf[s][3];
    const half8 Ac0 = An0, Ac1 = An1;
    if (kg < 14) {
      const char* bk = bsrc + (size_t)(kg + 2) * 16384;
#pragma unroll
      for (int m = 0; m < 4; ++m)
        Bf[s][m] = *(const half8*)(bk + m * 1024);
    }
    if (kg < 15) {
      const _Float16* ap = &Af[(kg + 1) * 2048 + jh * 1024 + lane * 8];
      An0 = *(const half8*)(ap);
      An1 = *(const half8*)(ap + 512);
    }
    MFMA16(Ac0, Bc0, acc0[0]); MFMA16(Ac0, Bc1, acc0[1]);
    MFMA16(Ac0, Bc2, acc0[2]); MFMA16(Ac0, Bc3, acc0[3]);
    MFMA16(Ac1, Bc0, acc1[0]); MFMA16(Ac1, Bc1, acc1[1]);
    MFMA16(Ac1, Bc2, acc1[2]); MFMA16(Ac1, Bc3, acc1[3]);
  }

  // ---- epilogue: lane holds acc0[m][r] -> (j = jh*32+q*4+r, h = hq*64+m*16+cc),
  //      acc1 = same with j+16. 4 h's and 8 j's per lane; 32 tv loads. ----
  const int hbase = hq * 64 + cc;
  const int j0    = jbase + jh * 32 + q * 4;

#define EPILOGUE(VROW, PRE) {                                                   \
    float tv0[16], tv1[16];                                                     \
    _Pragma("unroll")                                                           \
    for (int u = 0; u < 16; ++u) {                                              \
      const size_t jrow = (size_t)(j0 + (u & 3)) * HH + hbase + (u >> 2) * 16;  \
      tv0[u] = VROW[jrow];                                                      \
      tv1[u] = VROW[jrow + (size_t)16 * HH];                                    \
    }                                                                           \
    float w2v[4], pv[4];                                                        \
    _Pragma("unroll")                                                           \
    for (int m = 0; m < 4; ++m) {                                               \
      w2v[m] = w2_s[hbase + m * 16];                                            \
      pv[m]  = PRE[hbase + m * 16];                                             \
    }                                                                           \
    float p0[4], p1[4];                                                         \
    _Pragma("unroll")                                                           \
    for (int r = 0; r < 4; ++r) { p0[r] = 0.f; p1[r] = 0.f; }                   \
    _Pragma("unroll")                                                           \
    for (int u = 0; u < 16; ++u) {                                              \
      const int m = u >> 2, r = u & 3;                                          \
      const float hv0 = acc0[m][r] + pv[m] + tv0[u];                            \
      const float sv0 = hv0 * __builtin_amdgcn_rcpf(1.f + __expf(-hv0));        \
      p0[r] = fmaf(sv0, w2v[m], p0[r]);                                         \
      const float hv1 = acc1[m][r] + pv[m] + tv1[u];                            \
      const float sv1 = hv1 * __builtin_amdgcn_rcpf(1.f + __expf(-hv1));        \
      p1[r] = fmaf(sv1, w2v[m], p1[r]);                                         \
    }                                                                           \
    _Pragma("unroll")                                                           \
    for (int r = 0; r < 4; ++r) {                                               \
      float v = p0[r];                                                          \
      v = dpp_add<0xB1>(v);  v = dpp_add<0x4E>(v);                              \
      v = dpp_add<0x141>(v); v = dpp_add<0x140>(v);                             \
      if (cc == 0) sc_s[w][q * 4 + r] = v;                                      \
      float v2 = p1[r];                                                         \
      v2 = dpp_add<0xB1>(v2);  v2 = dpp_add<0x4E>(v2);                          \
      v2 = dpp_add<0x141>(v2); v2 = dpp_add<0x140>(v2);                         \
      if (cc == 0) sc_s[w][16 + q * 4 + r] = v2;                                \
    } }

  // direct: H = C + (S_i+b1) + T_j
  EPILOGUE(Tb, pre_s)
  __syncthreads();

  if (t < 64) {
    const int jh2 = t >> 5, jl = t & 31;
    float s = (sc_s[jh2 * 4 + 0][jl] + sc_s[jh2 * 4 + 1][jl]) +
              (sc_s[jh2 * 4 + 2][jl] + sc_s[jh2 * 4 + 3][jl]) + b2[0];
    const int jg2 = jbase + t;
    if (jg2 == i) s = NEGV;
    Sc[(size_t)bi * NN + jg2] = s;
  }

  // mirror (pure-upper blocks): H' = C + S_j + (T_i+b1)
  if (isUp) {
    __syncthreads();                // sc_s reads done before overwrite
    EPILOGUE(Sb, pre2_s)
    __syncthreads();
    if (t < 64) {
      const int jh2 = t >> 5, jl = t & 31;
      const float s = (sc_s[jh2 * 4 + 0][jl] + sc_s[jh2 * 4 + 1][jl]) +
                      (sc_s[jh2 * 4 + 2][jl] + sc_s[jh2 * 4 + 3][jl]) + b2[0];
      Sc[(size_t)(b * NN + jbase + t) * NN + i] = s;   // Sc[j, i]
    }
  }
#undef EPILOGUE
}

// ---------------- softmax: 1 wave per row, barrier-free ------------------------
__global__ __launch_bounds__(256) void softmax_kernel(const float* __restrict__ Sc,
                                                      float* __restrict__ out) {
  const int w    = threadIdx.x >> 6;        // wave 0..3
  const int lane = threadIdx.x & 63;
  const int bi   = blockIdx.x * 4 + w;      // row 0..1023
  const float4 v = *(const float4*)&Sc[(size_t)bi * NN + lane * 4];
  float m = fmaxf(fmaxf(v.x, v.y), fmaxf(v.z, v.w));
  m = fmaxf(m, __shfl_xor(m, 1));  m = fmaxf(m, __shfl_xor(m, 2));
  m = fmaxf(m, __shfl_xor(m, 4));  m = fmaxf(m, __shfl_xor(m, 8));
  m = fmaxf(m, __shfl_xor(m, 16)); m = fmaxf(m, __shfl_xor(m, 32));
  const float e0 = __expf(v.x - m), e1 = __expf(v.y - m);
  const float e2 = __expf(v.z - m), e3 = __expf(v.w - m);
  float sum = (e0 + e1) + (e2 + e3);
  sum += __shfl_xor(sum, 1);  sum += __shfl_xor(sum, 2);
  sum += __shfl_xor(sum, 4);  sum += __shfl_xor(sum, 8);
  sum += __shfl_xor(sum, 16); sum += __shfl_xor(sum, 32);
  const float r = 1.f / sum;
  float4 o; o.x = e0 * r; o.y = e1 * r; o.z = e2 * r; o.w = e3 * r;
  *(float4*)&out[(size_t)bi * NN + lane * 4] = o;
}

extern "C" void kernel_launch(void* const* d_in, const int* in_sizes, int n_in,
                              void* d_out, int out_size, void* d_ws, size_t ws_size,
                              hipStream_t stream) {
  const float* X  = (const float*)d_in[0];
  const float* W1 = (const float*)d_in[1];
  const float* b1 = (const float*)d_in[2];
  const float* W2 = (const float*)d_in[3];
  const float* b2 = (const float*)d_in[4];
  float* out = (float*)d_out;

  float*     Sws = (float*)d_ws;                             // 1 MB
  float*     Tws = Sws + (size_t)BB * NN * HH;               // 1 MB
  _Float16*  Wst = (_Float16*)(Tws + (size_t)BB * NN * HH);  // 256 KB
  float*     Scw = (float*)(Wst + (size_t)16 * HH * 32);     // 1 MB

  prep<<<256, 1024, 0, stream>>>(X, W1, Sws, Tws, Wst);
  score_mfma<<<dim3(640, BB), 512, 0, stream>>>(X, b1, W2, b2, Sws, Tws, Wst, Scw);
  softmax_kernel<<<BB * NN / 4, 256, 0, stream>>>(Scw, out);
}

// Round 15
// 154.250 us; speedup vs baseline: 1.0219x; 1.0219x over previous
//
#include <hip/hip_runtime.h>

#define BB 4
#define NN 256
#define DD 256
#define HH 256
#define NEGV -1.0e9f

typedef _Float16 half8 __attribute__((ext_vector_type(8)));
typedef __fp16   fp16x2 __attribute__((ext_vector_type(2)));
typedef float floatx4 __attribute__((ext_vector_type(4)));

// ---------------- prep (R27, kept): 256 blocks x 1024 thr, wave-split K --------
__global__ __launch_bounds__(1024) void prep(const float* __restrict__ X,
                                             const float* __restrict__ W1,
                                             float* __restrict__ S,
                                             float* __restrict__ T,
                                             _Float16* __restrict__ Wst) {
  const int g = blockIdx.x;    // 0..255 -> rows 4g..4g+3; Wst conversion d = g
  const int t = threadIdx.x;   // 0..1023

  __shared__ float xr[4][256];            // 4 KB
  __shared__ float part[2][4][4][256];    // 32 KB  [S/T][row][kq][h]

  if (t < 256) {   // weight conversion for d = g (R13 map, unchanged)
    const float wcv = W1[(size_t)(2 * DD + g) * HH + t];
    const float wdv = W1[(size_t)(3 * DD + g) * HH + t];
    const int ks = g >> 4;
    const int dd = g & 15;
    const int q  = dd >> 2;
    const int e  = (dd & 3) * 2;
    const int hgrp = t >> 4;
    const int ccw  = t & 15;
    _Float16* p = Wst + ((size_t)((ks * 16 + hgrp) * 4 + q) * 16 + ccw) * 8 + e;
    p[0] = (_Float16)wcv;
    p[1] = (_Float16)wdv;
  }

  const int row0 = g * 4;
  xr[t >> 8][t & 255] = X[(size_t)row0 * DD + t];
  __syncthreads();

  const int w    = t >> 6;     // wave 0..15
  const int lane = t & 63;
  const int r    = w >> 2;     // row 0..3
  const int kq   = w & 3;      // K-quarter 0..3
  const int h0   = lane * 4;
  const float* __restrict__ xrow = xr[r];
  const int dbase = kq * 64;

  float sa0 = 0.f, sa1 = 0.f, sa2 = 0.f, sa3 = 0.f;
  float sb0 = 0.f, sb1 = 0.f, sb2 = 0.f, sb3 = 0.f;
#pragma unroll 4
  for (int dd = 0; dd < 64; ++dd) {
    const int d = dbase + dd;
    const float4 wa = *(const float4*)&W1[(size_t)d * HH + h0];
    const float4 wb = *(const float4*)&W1[(size_t)(DD + d) * HH + h0];
    const float x = xrow[d];
    sa0 = fmaf(x, wa.x, sa0); sa1 = fmaf(x, wa.y, sa1);
    sa2 = fmaf(x, wa.z, sa2); sa3 = fmaf(x, wa.w, sa3);
    sb0 = fmaf(x, wb.x, sb0); sb1 = fmaf(x, wb.y, sb1);
    sb2 = fmaf(x, wb.z, sb2); sb3 = fmaf(x, wb.w, sb3);
  }
  *(float4*)&part[0][r][kq][h0] = make_float4(sa0, sa1, sa2, sa3);
  *(float4*)&part[1][r][kq][h0] = make_float4(sb0, sb1, sb2, sb3);
  __syncthreads();

  const int rr = t >> 8, hh = t & 255;
  S[(size_t)(row0 + rr) * HH + hh] =
      (part[0][rr][0][hh] + part[0][rr][1][hh]) +
      (part[0][rr][2][hh] + part[0][rr][3][hh]);
  T[(size_t)(row0 + rr) * HH + hh] =
      (part[1][rr][0][hh] + part[1][rr][1][hh]) +
      (part[1][rr][2][hh] + part[1][rr][3][hh]);
}

__device__ __forceinline__ half8 make_afrag(const float4 xi, const float4 xj) {
  fp16x2 p0 = __builtin_amdgcn_cvt_pkrtz(__builtin_fabsf(xi.x - xj.x), xi.x * xj.x);
  fp16x2 p1 = __builtin_amdgcn_cvt_pkrtz(__builtin_fabsf(xi.y - xj.y), xi.y * xj.y);
  fp16x2 p2 = __builtin_amdgcn_cvt_pkrtz(__builtin_fabsf(xi.z - xj.z), xi.z * xj.z);
  fp16x2 p3 = __builtin_amdgcn_cvt_pkrtz(__builtin_fabsf(xi.w - xj.w), xi.w * xj.w);
  uint4 u;
  u.x = __builtin_bit_cast(unsigned int, p0);
  u.y = __builtin_bit_cast(unsigned int, p1);
  u.z = __builtin_bit_cast(unsigned int, p2);
  u.w = __builtin_bit_cast(unsigned int, p3);
  return __builtin_bit_cast(half8, u);
}

#define MFMA16(af, bf, acc) acc = __builtin_amdgcn_mfma_f32_16x16x32_f16(af, bf, acc, 0, 0, 0)

// Cross-lane adds on the VALU pipe via DPP — zero DS-pipe ops (R30/R32).
// quad_perm(1,0,3,2)=0xB1 == xor1; quad_perm(2,3,0,1)=0x4E == xor2;
// row_half_mirror(0x141) pairs the same VALUES as xor4 (quad lanes identical
// after xor1+xor2); row_mirror(0x140) same values as xor8. FP add is bitwise
// commutative -> bit-identical to the shfl_xor butterfly. 16-lane reduce
// group == DPP row; row ops never cross groups.
template <int CTRL>
__device__ __forceinline__ float dpp_add(float v) {
  const int s = __builtin_amdgcn_update_dpp(0, __builtin_bit_cast(int, v),
                                            CTRL, 0xF, 0xF, true);
  return v + __builtin_bit_cast(float, s);
}

// ---------------- score: R32 FINAL (best-known: 84.4us score, 155.8us total) ---
// Session ledger: DS-pipe was the hidden critical pipe. R30 (xor1/2 -> DPP)
// -7.5us, R32 (xor4/8 -> mirror DPP) -4us, both predicted. R33's A-redundancy
// re-partition (32j x 64h) traded A-LDS for B-L2 redundancy and LOST 5us ->
// R32's 64j x 32h corner (A 8x LDS-redundant, B 1x) is the measured optimum.
// Occupancy frontier: 2 blocks/CU (R20/21/28: any launch-bounds squeeze below
// the ~110-reg natural footprint spills catastrophically). Not memory-bound
// (R29: -40% HBM traffic = no gain). Non-score time ~= 43us fixed harness
// floor + ~22us small kernels (R26 single-dispatch measurement).
__global__ __launch_bounds__(512, 4) void score_mfma(
    const float* __restrict__ X,  const float* __restrict__ b1,
    const float* __restrict__ W2, const float* __restrict__ b2,
    const float* __restrict__ S,  const float* __restrict__ T,
    const _Float16* __restrict__ Wst, float* __restrict__ Sc) {

  const int beta = blockIdx.x;      // 0..639, qt-major (R25 decode)
  const int b    = blockIdx.y;
  int i, qt;
  if (beta < 64)       { qt = 0; i = beta; }
  else if (beta < 192) { qt = 1; i = beta - 64; }
  else if (beta < 384) { qt = 2; i = beta - 192; }
  else                 { qt = 3; i = beta - 384; }
  const int bi    = b * NN + i;
  const int jbase = qt * 64;
  const int isUp  = qt > (i >> 6);  // block-uniform

  const int t     = threadIdx.x;    // 0..511
  const int lane  = t & 63;
  const int hg    = t >> 6;         // wave id 0..7 -> h-slice of 32
  const int q     = lane >> 4;
  const int cc    = lane & 15;

  __shared__ __align__(16) float    xi_s[DD];
  __shared__ __align__(16) _Float16 Af[32768];   // 64 KB
  __shared__ float pre_s[HH];
  __shared__ float pre2_s[HH];
  __shared__ float w2_s[HH];
  __shared__ float sc_s[8][64];

  if (t < 256) {
    xi_s[t]  = X[(size_t)bi * DD + t];
    pre_s[t] = S[(size_t)bi * HH + t] + b1[t];
  } else {
    const int u = t - 256;
    pre2_s[u] = T[(size_t)bi * HH + u] + b1[u];
    w2_s[u]   = W2[u];
  }

  const float* __restrict__ Tb = T + (size_t)b * NN * HH;
  const float* __restrict__ Sb = S + (size_t)b * NN * HH;

  const int jloc = t & 63;
  const int jg   = jloc >> 4;
  const int ccw  = jloc & 15;
  const float* __restrict__ xjrow = X + (size_t)(b * NN + jbase + jloc) * DD;

  const char* __restrict__ bsrc = (const char*)Wst + hg * 2048 + (size_t)lane * 16;

  half8 Bf0[4], Bf1[4];
#pragma unroll
  for (int u = 0; u < 4; ++u) {
    Bf0[u] = *(const half8*)(bsrc + (size_t)u * 16384);
    Bf1[u] = *(const half8*)(bsrc + (size_t)u * 16384 + 1024);
  }

  __syncthreads();                  // header (xi_s) ready

  {
    const int sgrp = t >> 6;
#pragma unroll
    for (int idx = 0; idx < 8; ++idx) {
      const int ksqg = sgrp * 8 + idx;          // 0..63 k-quads
      const int d0   = ksqg * 4;
      const int kg   = ksqg >> 2;               // 0..15
      const int qw   = ksqg & 3;
      const float4 xi4 = *(const float4*)&xi_s[d0];
      const float4 xj4 = *(const float4*)(xjrow + d0);
      *(half8*)&Af[kg * 2048 + (jg * 4 + qw) * 128 + ccw * 8] = make_afrag(xi4, xj4);
    }
  }
  __syncthreads();                  // Af ready; K-loop barrier-free, 16 steps

  floatx4 acc0[4], acc1[4];
#pragma unroll
  for (int u = 0; u < 4; ++u) { acc0[u] = (floatx4)0.f; acc1[u] = (floatx4)0.f; }

  const _Float16* ap0 = &Af[lane * 8];
  half8 An0 = *(const half8*)(ap0);
  half8 An1 = *(const half8*)(ap0 + 512);
  half8 An2 = *(const half8*)(ap0 + 1024);
  half8 An3 = *(const half8*)(ap0 + 1536);

#pragma unroll
  for (int kg = 0; kg < 16; ++kg) {
    const int s = kg & 3;
    const half8 Bc0 = Bf0[s], Bc1 = Bf1[s];
    const half8 Ac0 = An0, Ac1 = An1, Ac2 = An2, Ac3 = An3;
    if (kg < 12) {
      const char* bk = bsrc + (size_t)(kg + 4) * 16384;
      Bf0[s] = *(const half8*)(bk);
      Bf1[s] = *(const half8*)(bk + 1024);
    }
    if (kg < 15) {
      const _Float16* ap = &Af[(kg + 1) * 2048 + lane * 8];
      An0 = *(const half8*)(ap);
      An1 = *(const half8*)(ap + 512);
      An2 = *(const half8*)(ap + 1024);
      An3 = *(const half8*)(ap + 1536);
    }
    MFMA16(Ac0, Bc0, acc0[0]); MFMA16(Ac0, Bc1, acc1[0]);
    MFMA16(Ac1, Bc0, acc0[1]); MFMA16(Ac1, Bc1, acc1[1]);
    MFMA16(Ac2, Bc0, acc0[2]); MFMA16(Ac2, Bc1, acc1[2]);
    MFMA16(Ac3, Bc0, acc0[3]); MFMA16(Ac3, Bc1, acc1[3]);
  }

  const int h0   = hg * 32 + cc;
  const int h1   = h0 + 16;
  const int jrow = jbase + q * 4;

#define EPILOGUE(VROW, PRE) {                                                   \
    float tv0[16], tv1[16];                                                     \
    _Pragma("unroll")                                                           \
    for (int u = 0; u < 16; ++u) {                                              \
      const size_t j = (size_t)(jrow + (u >> 2) * 16 + (u & 3)) * HH;           \
      tv0[u] = VROW[j + h0];                                                    \
      tv1[u] = VROW[j + h1];                                                    \
    }                                                                           \
    const float w20 = w2_s[h0], pv0 = PRE[h0];                                  \
    const float w21 = w2_s[h1], pv1 = PRE[h1];                                  \
    float p[16];                                                                \
    _Pragma("unroll")                                                           \
    for (int u = 0; u < 16; ++u) {                                              \
      const float hv0 = acc0[u >> 2][u & 3] + pv0 + tv0[u];                     \
      const float sv0 = hv0 * __builtin_amdgcn_rcpf(1.f + __expf(-hv0));        \
      p[u] = sv0 * w20;                                                         \
      const float hv1 = acc1[u >> 2][u & 3] + pv1 + tv1[u];                     \
      const float sv1 = hv1 * __builtin_amdgcn_rcpf(1.f + __expf(-hv1));        \
      p[u] = fmaf(sv1, w21, p[u]);                                              \
    }                                                                           \
    _Pragma("unroll")                                                           \
    for (int u = 0; u < 16; ++u) {                                              \
      float v = p[u];                                                           \
      v = dpp_add<0xB1>(v);    /* xor1: quad_perm(1,0,3,2) */                   \
      v = dpp_add<0x4E>(v);    /* xor2: quad_perm(2,3,0,1) */                   \
      v = dpp_add<0x141>(v);   /* xor4-equivalent: row_half_mirror */           \
      v = dpp_add<0x140>(v);   /* xor8-equivalent: row_mirror */                \
      if (cc == 0) sc_s[hg][(u >> 2) * 16 + q * 4 + (u & 3)] = v;               \
    } }

  EPILOGUE(Tb, pre_s)
  __syncthreads();

  if (t < 64) {
    float s = sc_s[0][t] + sc_s[1][t] + sc_s[2][t] + sc_s[3][t]
            + sc_s[4][t] + sc_s[5][t] + sc_s[6][t] + sc_s[7][t] + b2[0];
    const int jg2 = jbase + t;
    if (jg2 == i) s = NEGV;
    Sc[(size_t)bi * NN + jg2] = s;
  }

  if (isUp) {
    __syncthreads();
    EPILOGUE(Sb, pre2_s)
    __syncthreads();
    if (t < 64) {
      const float s = sc_s[0][t] + sc_s[1][t] + sc_s[2][t] + sc_s[3][t]
                    + sc_s[4][t] + sc_s[5][t] + sc_s[6][t] + sc_s[7][t] + b2[0];
      Sc[(size_t)(b * NN + jbase + t) * NN + i] = s;   // Sc[j, i]
    }
  }
#undef EPILOGUE
}

// ---------------- softmax: 1 wave per row, barrier-free ------------------------
__global__ __launch_bounds__(256) void softmax_kernel(const float* __restrict__ Sc,
                                                      float* __restrict__ out) {
  const int w    = threadIdx.x >> 6;        // wave 0..3
  const int lane = threadIdx.x & 63;
  const int bi   = blockIdx.x * 4 + w;      // row 0..1023
  const float4 v = *(const float4*)&Sc[(size_t)bi * NN + lane * 4];
  float m = fmaxf(fmaxf(v.x, v.y), fmaxf(v.z, v.w));
  m = fmaxf(m, __shfl_xor(m, 1));  m = fmaxf(m, __shfl_xor(m, 2));
  m = fmaxf(m, __shfl_xor(m, 4));  m = fmaxf(m, __shfl_xor(m, 8));
  m = fmaxf(m, __shfl_xor(m, 16)); m = fmaxf(m, __shfl_xor(m, 32));
  const float e0 = __expf(v.x - m), e1 = __expf(v.y - m);
  const float e2 = __expf(v.z - m), e3 = __expf(v.w - m);
  float sum = (e0 + e1) + (e2 + e3);
  sum += __shfl_xor(sum, 1);  sum += __shfl_xor(sum, 2);
  sum += __shfl_xor(sum, 4);  sum += __shfl_xor(sum, 8);
  sum += __shfl_xor(sum, 16); sum += __shfl_xor(sum, 32);
  const float r = 1.f / sum;
  float4 o; o.x = e0 * r; o.y = e1 * r; o.z = e2 * r; o.w = e3 * r;
  *(float4*)&out[(size_t)bi * NN + lane * 4] = o;
}

extern "C" void kernel_launch(void* const* d_in, const int* in_sizes, int n_in,
                              void* d_out, int out_size, void* d_ws, size_t ws_size,
                              hipStream_t stream) {
  const float* X  = (const float*)d_in[0];
  const float* W1 = (const float*)d_in[1];
  const float* b1 = (const float*)d_in[2];
  const float* W2 = (const float*)d_in[3];
  const float* b2 = (const float*)d_in[4];
  float* out = (float*)d_out;

  float*     Sws = (float*)d_ws;                             // 1 MB
  float*     Tws = Sws + (size_t)BB * NN * HH;               // 1 MB
  _Float16*  Wst = (_Float16*)(Tws + (size_t)BB * NN * HH);  // 256 KB
  float*     Scw = (float*)(Wst + (size_t)16 * HH * 32);     // 1 MB

  prep<<<256, 1024, 0, stream>>>(X, W1, Sws, Tws, Wst);
  score_mfma<<<dim3(640, BB), 512, 0, stream>>>(X, b1, W2, b2, Sws, Tws, Wst, Scw);
  softmax_kernel<<<BB * NN / 4, 256, 0, stream>>>(Scw, out);
}